// Round 6
// baseline (222.051 us; speedup 1.0000x reference)
//
#include <hip/hip_runtime.h>

typedef unsigned short u16;
typedef __bf16 bf16x8 __attribute__((ext_vector_type(8)));
typedef float f32x4 __attribute__((ext_vector_type(4)));

// Problem constants (from reference)
#define NB 16      // batches
#define NC 64      // channels
#define NK 207     // nodes (K_DIM)
#define NL 64      // time (L_DIM)
#define KP 224     // padded GEMM K-dim over nodes (207 -> 224 = 7*32)
#define NKL 13248  // NK*NL
#define CIN 320

// Fragment-major layouts: one MFMA A/B operand tile (16 rows x 32 k, bf16)
// = 512 contiguous u16 = 1 KB. Element (row r16, k=ks*32+q*8+e) lives at
// tile*512 + (r16 + 16*q)*8 + e.
//   Xf [b][tile=l*4+(c>>4)][ks]  tile<256, ks<7   (row = l*64+c, k = node)
//   Gf [b][p][jt][ks]            p<5, jt<13, ks<7 (row = j, k = node)
//   Wf [ot][ks]                  ot<4, ks<10      (row = o, k = cin)

__device__ __forceinline__ u16 f2bf(float f) {
  unsigned u = __builtin_bit_cast(unsigned, f);
  u += 0x7FFFu + ((u >> 16) & 1u);   // RNE; inputs are never NaN
  return (u16)(u >> 16);
}

// async global->LDS, 16 B per lane. ldst must be (wave-uniform base + lane*16).
__device__ __forceinline__ void g2l16(const u16* gsrc, u16* ldst) {
  __builtin_amdgcn_global_load_lds(
      (const __attribute__((address_space(1))) unsigned int*)gsrc,
      (__attribute__((address_space(3))) unsigned int*)ldst, 16, 0, 0);
}

// ---- prep-x: x -> Xf (+ W -> Wf) -------------------------------------------
// [0,512): Block=(b, c4, lh, ksh): 16 channels, 16 l, 3-4 ks.
//   Phase A: lane = consecutive k, reads one FULL 64B line (16 l fp32)
//   per (c,k); scalar bf16 scatter into fragment-shaped LDS.
//   Phase B: wave-contiguous b128 LDS read + 1KB-contiguous fragment store.
// 512: W -> Wf.
__global__ __launch_bounds__(256) void k_prepx(
    const float* __restrict__ x, const float* __restrict__ W,
    u16* __restrict__ Xf, u16* __restrict__ Wbf) {
  __shared__ __align__(16) u16 xs[16 * 2048];   // 64 KB: [ll][ksl(4)][512]
  int id = blockIdx.x, t = threadIdx.x;
  if (id < 512) {
    int b = id >> 5, rem = id & 31;
    int c4 = rem >> 3, lh = (rem >> 1) & 3, ksh = rem & 1;
    int ks0 = ksh ? 4 : 0, nks = ksh ? 3 : 4;
    int kw = nks * 32;                 // 128 or 96
    int l0 = lh * 16;
    int cl = t >> 4, kl = t & 15;
    const float* xc = x + (size_t)(b * 64 + c4 * 16 + cl) * NKL;
    for (int kk = kl; kk < kw; kk += 16) {
      int k = ksh * 128 + kk;
      float4 v0 = {0.f, 0.f, 0.f, 0.f}, v1 = v0, v2 = v0, v3 = v0;
      if (k < NK) {
        const float4* p = (const float4*)(xc + (size_t)k * 64 + l0);
        v0 = p[0]; v1 = p[1]; v2 = p[2]; v3 = p[3];
      }
      int ksl = kk >> 5, q = (kk >> 3) & 3, e = kk & 7;
      u16* dst = &xs[ksl * 512 + (cl + 16 * q) * 8 + e];   // +ll*2048
      dst[0 * 2048] = f2bf(v0.x);  dst[1 * 2048] = f2bf(v0.y);
      dst[2 * 2048] = f2bf(v0.z);  dst[3 * 2048] = f2bf(v0.w);
      dst[4 * 2048] = f2bf(v1.x);  dst[5 * 2048] = f2bf(v1.y);
      dst[6 * 2048] = f2bf(v1.z);  dst[7 * 2048] = f2bf(v1.w);
      dst[8 * 2048] = f2bf(v2.x);  dst[9 * 2048] = f2bf(v2.y);
      dst[10 * 2048] = f2bf(v2.z); dst[11 * 2048] = f2bf(v2.w);
      dst[12 * 2048] = f2bf(v3.x); dst[13 * 2048] = f2bf(v3.y);
      dst[14 * 2048] = f2bf(v3.z); dst[15 * 2048] = f2bf(v3.w);
    }
    __syncthreads();
    int wavei = t >> 6, lane = t & 63;
    u16* Xb = Xf + (size_t)b * 256 * 7 * 512;
    for (int ll = wavei; ll < 16; ll += 4) {
      int l = l0 + ll;
      for (int ksl = 0; ksl < nks; ksl++) {
        bf16x8 v = *(const bf16x8*)&xs[ll * 2048 + ksl * 512 + lane * 8];
        *(bf16x8*)(Xb + ((size_t)(l * 4 + c4) * 7 + ks0 + ksl) * 512 +
                   lane * 8) = v;
      }
    }
  } else {
    for (int ci = t; ci < 2560; ci += 256) {
      int o = ci / 40, kc = ci - o * 40;
      u16 v[8] __attribute__((aligned(16)));
      for (int j = 0; j < 8; j++) v[j] = f2bf(W[o * CIN + kc * 8 + j]);
      *(int4*)(Wbf + ((size_t)(o >> 4) * 10 + (kc >> 2)) * 512 +
               ((o & 15) + 16 * (kc & 3)) * 8) = *(int4*)v;
    }
  }
}

// ---- prep-a: self-contained A path. One block per (b,w); 512 thr; 126KB LDS.
// Arow frags [14 tiles][7 ks][512] (98 KB) | Acol chunk [4 tiles][7][512] (28 KB)
//  1. A row-wise  -> Arow LDS (zero-padded to 224x224)
//  2. Arow tiles 0..12 -> Gf p=1,3 (straight 91 x 1KB fragment copy)
//  3. w==0 blocks write Gf p=0 identity
//  4. per 64-col chunk: A col-wise -> Acol LDS; MFMA A^2 -> Gf p=2,4
// Replaces the old A-branches of k_prep AND the whole k_asq kernel
// (no Af/Atf global round-trip, one less launch).
#define ACOL 50176
__global__ __launch_bounds__(512) void k_prepa(
    const float* __restrict__ a0, const float* __restrict__ a1,
    u16* __restrict__ Gf) {
  __shared__ __align__(16) u16 al[64512];   // 129,024 B
  int bw = blockIdx.x;
  int b = bw >> 1, w = bw & 1;
  int t = threadIdx.x;
  int wave = t >> 6, lane = t & 63;
  int r = lane & 15, q = lane >> 4;
  const float* A = (w ? a1 : a0) + (size_t)b * NK * NK;

  // 1. row-load -> Arow frags (224 rows x 28 kc-chunks)
  for (int u = t; u < 6272; u += 512) {
    int m = u / 28, kc = u - m * 28;
    u16 v[8] __attribute__((aligned(16)));
#pragma unroll
    for (int j = 0; j < 8; j++) {
      int k = kc * 8 + j;
      v[j] = (m < NK && k < NK) ? f2bf(A[(size_t)m * NK + k]) : (u16)0;
    }
    *(int4*)&al[((m >> 4) * 7 + (kc >> 2)) * 512 +
                ((m & 15) + 16 * (kc & 3)) * 8] = *(int4*)v;
  }
  __syncthreads();

  // 2. Gf p=1,3: frag f = jt*7+ks identical in LDS and Gf -> direct copy
  u16* Gp13 = Gf + ((size_t)b * 5 + 1 + 2 * w) * 13 * 7 * 512;
  for (int f = wave; f < 91; f += 8) {
    bf16x8 v = *(const bf16x8*)&al[(size_t)f * 512 + lane * 8];
    *(bf16x8*)(Gp13 + (size_t)f * 512 + lane * 8) = v;
  }

  // 3. identity p=0 (computed, no LDS)
  if (w == 0) {
    u16* Gp0 = Gf + (size_t)b * 5 * 13 * 7 * 512;
    for (int u = t; u < 91 * 64; u += 512) {
      int f = u >> 6, pos = u & 63;
      int jt = f / 7, ks = f - jt * 7;
      int j = jt * 16 + (pos & 15), qq = pos >> 4;
      u16 v[8] __attribute__((aligned(16)));
#pragma unroll
      for (int e = 0; e < 8; e++) {
        int k = ks * 32 + qq * 8 + e;
        v[e] = (j == k && j < NK) ? (u16)0x3F80 : (u16)0;
      }
      *(int4*)(Gp0 + (size_t)f * 512 + pos * 8) = *(int4*)v;
    }
  }

  // 4. A^2 in 4 uniform chunks of 64 cols (chunk 3 tiles >=14 fully guarded)
  u16* Gp24 = Gf + ((size_t)b * 5 + 2 + 2 * w) * 13 * 7 * 512;
  for (int ch = 0; ch < 4; ch++) {
    int n0 = ch * 64;
    __syncthreads();                 // previous chunk's MFMAs done
    {
      int n = n0 + lane;             // lanes = 64 consecutive cols: 256B reads
      for (int mi = 0; mi < 28; mi++) {
        int m = wave * 28 + mi;      // covers 0..223
        u16 v = (n < NK && m < NK) ? f2bf(A[(size_t)m * NK + n]) : (u16)0;
        al[ACOL + ((lane >> 4) * 7 + (m >> 5)) * 512 +
           ((lane & 15) + 16 * ((m >> 3) & 3)) * 8 + (m & 7)] = v;
      }
    }
    __syncthreads();
    for (int o = wave; o < 56; o += 8) {
      int mt = o >> 2, nt = o & 3;
      f32x4 acc = {};
#pragma unroll
      for (int ks = 0; ks < 7; ks++) {
        bf16x8 af = *(const bf16x8*)&al[(mt * 7 + ks) * 512 + lane * 8];
        bf16x8 bg = *(const bf16x8*)&al[ACOL + (nt * 7 + ks) * 512 + lane * 8];
        acc = __builtin_amdgcn_mfma_f32_16x16x32_bf16(af, bg, acc, 0, 0, 0);
      }
#pragma unroll
      for (int rr = 0; rr < 4; rr++) {
        int mj = mt * 16 + q * 4 + rr;
        int nk = n0 + nt * 16 + r;
        if (mj < 208 && nk < KP)
          Gp24[((size_t)(mj >> 4) * 7 + (nk >> 5)) * 512 +
               ((mj & 15) + 16 * ((nk >> 3) & 3)) * 8 + (nk & 7)] =
              f2bf(acc[rr]);
      }
    }
  }
}

// ---- fused diffuse+conv (unchanged: 55 us, known-good) ---------------------
#define AG 17920            // A-stage base (u16); G region is [0, 17920)
__global__ __launch_bounds__(512, 4) void k_fused(
    const u16* __restrict__ Gf, const u16* __restrict__ Xf,
    const u16* __restrict__ Wbf, const float* __restrict__ bias,
    float* __restrict__ y) {
  __shared__ __align__(16) u16 lds[AG + 2 * 8192];  // 68,608 B -> 2 blocks/CU
  // bijective XCD swizzle: 3328 blocks, 416/XCD = 2 batches worth
  int id = blockIdx.x;
  int wg = (id & 7) * 416 + (id >> 3);
  int b = wg / 208, rem = wg % 208;
  int jt = rem >> 4, lt = rem & 15;
  int tid = threadIdx.x, wave = tid >> 6, lane = tid & 63;
  int r = lane & 15, q = lane >> 4;
  const u16* Gb = Gf + (size_t)b * 5 * 13 * 7 * 512;
  const u16* Xw = Xf + ((size_t)b * 256 + lt * 16) * 7 * 512;  // 16 tiles

  // stage G: 35 fragment tiles (p*7+ks), each one contiguous 1 KB DMA
  for (int i2 = 0; i2 < 5; i2++) {
    int tile = i2 * 8 + wave;            // wave-uniform
    if (tile < 35) {
      int p = tile / 7, ks = tile - p * 7;
      g2l16(Gb + ((size_t)(p * 13 + jt) * 7 + ks) * 512 + lane * 8,
            &lds[tile * 512 + lane * 8]);
    }
  }
  // prologue: stage ks=0 into buf0 (wave-private tiles wave*2+{0,1})
  for (int i2 = 0; i2 < 2; i2++) {
    int tl = wave * 2 + i2;
    g2l16(Xw + (size_t)tl * 7 * 512 + lane * 8, &lds[AG + tl * 512 + lane * 8]);
  }
  asm volatile("s_waitcnt vmcnt(2)" ::: "memory");  // G landed; stage0 in flight
  __builtin_amdgcn_s_barrier();                     // G visible to all waves

  f32x4 acc1[5][2] = {};
#pragma unroll
  for (int ks = 0; ks < 7; ks++) {
    int cur = ks & 1;
    if (ks < 6) {                      // stage ks+1 into other buffer
      for (int i2 = 0; i2 < 2; i2++) {
        int tl = wave * 2 + i2;
        g2l16(Xw + ((size_t)tl * 7 + ks + 1) * 512 + lane * 8,
              &lds[AG + (cur ^ 1) * 8192 + tl * 512 + lane * 8]);
      }
      asm volatile("s_waitcnt vmcnt(2)" ::: "memory");  // buf[cur] ready (mine)
    } else {
      asm volatile("s_waitcnt vmcnt(0)" ::: "memory");
    }
    bf16x8 af0 = *(const bf16x8*)&lds[AG + cur * 8192 + (wave * 2 + 0) * 512 + lane * 8];
    bf16x8 af1 = *(const bf16x8*)&lds[AG + cur * 8192 + (wave * 2 + 1) * 512 + lane * 8];
    __builtin_amdgcn_s_setprio(1);
#pragma unroll
    for (int p = 0; p < 5; p++) {
      bf16x8 bg = *(const bf16x8*)&lds[(p * 7 + ks) * 512 + lane * 8];
      acc1[p][0] = __builtin_amdgcn_mfma_f32_16x16x32_bf16(af0, bg, acc1[p][0], 0, 0, 0);
      acc1[p][1] = __builtin_amdgcn_mfma_f32_16x16x32_bf16(af1, bg, acc1[p][1], 0, 0, 0);
    }
    __builtin_amdgcn_s_setprio(0);
  }
  __syncthreads();   // all waves done with G + A-stage; reuse LDS for T

  // write T[p][j][t][c] (stride 72 u16, 16B-aligned rows; c XOR-swizzle by j)
#pragma unroll
  for (int p = 0; p < 5; p++)
#pragma unroll
    for (int mf = 0; mf < 2; mf++) {
      int m = (wave * 2 + mf) * 16 + q * 4;
      int tt = m >> 6, c = m & 63;
      int cs = c ^ ((r & 7) << 3);
      int idxT = ((p * 16 + r) * 4 + tt) * 72 + cs;
      u16 v0 = f2bf(acc1[p][mf][0]), v1 = f2bf(acc1[p][mf][1]);
      u16 v2 = f2bf(acc1[p][mf][2]), v3 = f2bf(acc1[p][mf][3]);
      *(uint2*)&lds[idxT] = make_uint2((unsigned)v0 | ((unsigned)v1 << 16),
                                       (unsigned)v2 | ((unsigned)v3 << 16));
    }
  // prefetch all W fragments to VGPRs (contiguous from Wf); fly across barrier
  int mo = wave >> 1, nh = (wave & 1) * 2;
  const u16* Wt = Wbf + (size_t)mo * 10 * 512 + lane * 8;
  bf16x8 aw[10];
#pragma unroll
  for (int ks = 0; ks < 10; ks++) aw[ks] = *(const bf16x8*)(Wt + ks * 512);
  __syncthreads();

  // GEMM-2: y tile 64(o) x 64(j,t), K=320=(p,c). No barriers.
  f32x4 acc2[2] = {};
#pragma unroll
  for (int ks = 0; ks < 10; ks++) {
    int p = ks >> 1, c0 = (ks & 1) * 32;
#pragma unroll
    for (int nf = 0; nf < 2; nf++) {
      int n = (nh + nf) * 16 + r;
      int j = n >> 2, tt = n & 3;
      int cs = (c0 + q * 8) ^ ((j & 7) << 3);
      bf16x8 bt = *(const bf16x8*)&lds[((p * 16 + j) * 4 + tt) * 72 + cs];
      acc2[nf] = __builtin_amdgcn_mfma_f32_16x16x32_bf16(aw[ks], bt, acc2[nf], 0, 0, 0);
    }
  }

  // epilogue: per (o, j) the 4 t-values are 16B-contiguous in y
  int o0 = mo * 16 + q * 4;
  float4 bv = *(const float4*)&bias[o0];
  float* yb = y + (size_t)b * 64 * NKL;
#pragma unroll
  for (int nf = 0; nf < 2; nf++) {
    int n = (nh + nf) * 16 + r;
    int j = n >> 2, tt = n & 3;
    int jnode = jt * 16 + j;
    if (jnode < NK) {
      int col = jnode * 64 + lt * 4 + tt;
      yb[(size_t)(o0 + 0) * NKL + col] = acc2[nf][0] + bv.x;
      yb[(size_t)(o0 + 1) * NKL + col] = acc2[nf][1] + bv.y;
      yb[(size_t)(o0 + 2) * NKL + col] = acc2[nf][2] + bv.z;
      yb[(size_t)(o0 + 3) * NKL + col] = acc2[nf][3] + bv.w;
    }
  }
}

extern "C" void kernel_launch(void* const* d_in, const int* in_sizes, int n_in,
                              void* d_out, int out_size, void* d_ws, size_t ws_size,
                              hipStream_t stream) {
  const float* x = (const float*)d_in[0];
  const float* a0 = (const float*)d_in[1];
  const float* a1 = (const float*)d_in[2];
  const float* W = (const float*)d_in[3];
  const float* bias = (const float*)d_in[4];
  float* y = (float*)d_out;
  char* ws = (char*)d_ws;

  size_t off = 0;
  auto alloc = [&](size_t bytes) {
    size_t o = off;
    off = (off + bytes + 511) & ~(size_t)511;
    return o;
  };
  size_t o_Xf = alloc((size_t)NB * 256 * 7 * 512 * 2);       // 29.4 MB
  size_t o_Gf = alloc((size_t)NB * 5 * 13 * 7 * 512 * 2);    // 7.5 MB
  size_t o_Wf = alloc((size_t)4 * 10 * 512 * 2);             // 40 KB
  (void)ws_size;

  u16* Xf = (u16*)(ws + o_Xf);
  u16* Gf = (u16*)(ws + o_Gf);
  u16* Wf = (u16*)(ws + o_Wf);

  k_prepa<<<dim3(32), 512, 0, stream>>>(a0, a1, Gf);
  k_prepx<<<dim3(513), 256, 0, stream>>>(x, W, Xf, Wf);
  k_fused<<<dim3(16 * 13 * 16), 512, 0, stream>>>(Gf, Xf, Wf, bias, y);
}

// Round 7
// 208.907 us; speedup vs baseline: 1.0629x; 1.0629x over previous
//
#include <hip/hip_runtime.h>

typedef unsigned short u16;
typedef __bf16 bf16x8 __attribute__((ext_vector_type(8)));
typedef float f32x4 __attribute__((ext_vector_type(4)));

// Problem constants (from reference)
#define NB 16      // batches
#define NC 64      // channels
#define NK 207     // nodes (K_DIM)
#define NL 64      // time (L_DIM)
#define KP 224     // padded GEMM K-dim over nodes (207 -> 224 = 7*32)
#define NKL 13248  // NK*NL
#define CIN 320

// Fragment-major layouts: one MFMA A/B operand tile (16 rows x 32 k, bf16)
// = 512 contiguous u16 = 1 KB. Element (row r16, k=ks*32+q*8+e) lives at
// tile*512 + (r16 + 16*q)*8 + e.
//   Xf [b][tile=l*4+(c>>4)][ks]  tile<256, ks<7   (row = l*64+c, k = node)
//   Gf [b][p][jt][ks]            p<5, jt<13, ks<7 (row = j, k = node)
//   Wf [ot][ks]                  ot<4, ks<10      (row = o, k = cin)

__device__ __forceinline__ u16 f2bf(float f) {
  unsigned u = __builtin_bit_cast(unsigned, f);
  u += 0x7FFFu + ((u >> 16) & 1u);   // RNE; inputs are never NaN
  return (u16)(u >> 16);
}

// async global->LDS, 16 B per lane. ldst must be (wave-uniform base + lane*16).
__device__ __forceinline__ void g2l16(const u16* gsrc, u16* ldst) {
  __builtin_amdgcn_global_load_lds(
      (const __attribute__((address_space(1))) unsigned int*)gsrc,
      (__attribute__((address_space(3))) unsigned int*)ldst, 16, 0, 0);
}

// ---- merged prep: one wide launch, branch by block range (wave-uniform) ----
// [0,512)     : x -> Xf. Block=(b, c4, lh, ksh). Phase A: full-64B-line reads,
//               scatter to fragment-shaped LDS. Phase B: 1KB-contiguous stores.
// [512,1024)  : A^2 -> Gf p=2,4. Block=(bw, 64x64 tile). Gathers its 64 rows
//               + 64 cols of fp32 A (L2-hot) into frag LDS, 112 MFMAs, store.
//               Replaces k_asq with NO Af/Atf global round-trip.
// [1024,1280) : A rows -> Gf p=1,3 (gather-copy, 26 rows/block).
// [1280,1312) : Gf p=0 identity.
// 1312        : W -> Wf.
__global__ __launch_bounds__(256) void k_prep(
    const float* __restrict__ x, const float* __restrict__ a0,
    const float* __restrict__ a1, const float* __restrict__ W,
    u16* __restrict__ Xf, u16* __restrict__ Gf, u16* __restrict__ Wbf) {
  __shared__ __align__(16) u16 sm[32768];   // 64 KB
  int id = blockIdx.x, t = threadIdx.x;
  if (id < 512) {
    int b = id >> 5, rem = id & 31;
    int c4 = rem >> 3, lh = (rem >> 1) & 3, ksh = rem & 1;
    int ks0 = ksh ? 4 : 0, nks = ksh ? 3 : 4;
    int kw = nks * 32;                 // 128 or 96
    int l0 = lh * 16;
    int cl = t >> 4, kl = t & 15;
    const float* xc = x + (size_t)(b * 64 + c4 * 16 + cl) * NKL;
    // phase A: per (c,k) read full 64B line (16 l), convert, scatter to LDS
    for (int kk = kl; kk < kw; kk += 16) {
      int k = ksh * 128 + kk;
      float4 v0 = {0.f, 0.f, 0.f, 0.f}, v1 = v0, v2 = v0, v3 = v0;
      if (k < NK) {
        const float4* p = (const float4*)(xc + (size_t)k * 64 + l0);
        v0 = p[0]; v1 = p[1]; v2 = p[2]; v3 = p[3];
      }
      int ksl = kk >> 5, q = (kk >> 3) & 3, e = kk & 7;
      u16* dst = &sm[ksl * 512 + (cl + 16 * q) * 8 + e];   // +ll*2048
      dst[0 * 2048] = f2bf(v0.x);  dst[1 * 2048] = f2bf(v0.y);
      dst[2 * 2048] = f2bf(v0.z);  dst[3 * 2048] = f2bf(v0.w);
      dst[4 * 2048] = f2bf(v1.x);  dst[5 * 2048] = f2bf(v1.y);
      dst[6 * 2048] = f2bf(v1.z);  dst[7 * 2048] = f2bf(v1.w);
      dst[8 * 2048] = f2bf(v2.x);  dst[9 * 2048] = f2bf(v2.y);
      dst[10 * 2048] = f2bf(v2.z); dst[11 * 2048] = f2bf(v2.w);
      dst[12 * 2048] = f2bf(v3.x); dst[13 * 2048] = f2bf(v3.y);
      dst[14 * 2048] = f2bf(v3.z); dst[15 * 2048] = f2bf(v3.w);
    }
    __syncthreads();
    // phase B: each wave stores whole 1KB fragments, contiguous both sides
    int wavei = t >> 6, lane = t & 63;
    u16* Xb = Xf + (size_t)b * 256 * 7 * 512;
    for (int ll = wavei; ll < 16; ll += 4) {
      int l = l0 + ll;
      for (int ksl = 0; ksl < nks; ksl++) {
        bf16x8 v = *(const bf16x8*)&sm[ll * 2048 + ksl * 512 + lane * 8];
        *(bf16x8*)(Xb + ((size_t)(l * 4 + c4) * 7 + ks0 + ksl) * 512 +
                   lane * 8) = v;
      }
    }
  } else if (id < 1024) {
    // A^2 64x64 tile: rows m0..m0+63 (A-op), cols n0..n0+63 (B-op)
    int local = id - 512;
    int bw = local >> 4, tp = local & 15;
    int b = bw >> 1, w = bw & 1;
    int m0 = (tp >> 2) * 64, n0 = (tp & 3) * 64;
    const float* A = (w ? a1 : a0) + (size_t)b * NK * NK;
    // sm: A-row frags [4][7][512] at 0; A-col frags [4][7][512] at 14336
    for (int u = t; u < 64 * 28; u += 256) {          // row gather
      int ml = u / 28, kc = u - ml * 28;
      int m = m0 + ml;
      u16 v[8] __attribute__((aligned(16)));
#pragma unroll
      for (int j = 0; j < 8; j++) {
        int k = kc * 8 + j;
        v[j] = (m < NK && k < NK) ? f2bf(A[(size_t)m * NK + k]) : (u16)0;
      }
      *(int4*)&sm[((ml >> 4) * 7 + (kc >> 2)) * 512 +
                  ((ml & 15) + 16 * (kc & 3)) * 8] = *(int4*)v;
    }
    {                                                  // col gather (B-op)
      int nl = t & 63, mq = t >> 6;
      int n = n0 + nl;
      for (int mi = 0; mi < 56; mi++) {
        int m = mq * 56 + mi;                          // 0..223
        u16 v = (n < NK && m < NK) ? f2bf(A[(size_t)m * NK + n]) : (u16)0;
        sm[14336 + ((nl >> 4) * 7 + (m >> 5)) * 512 +
           ((nl & 15) + 16 * ((m >> 3) & 3)) * 8 + (m & 7)] = v;
      }
    }
    __syncthreads();
    int lane = t & 63, wave = t >> 6;
    int r = lane & 15, q = lane >> 4;
    u16* Gp24 = Gf + ((size_t)b * 5 + 2 + 2 * w) * 13 * 7 * 512;
    for (int o = wave; o < 16; o += 4) {
      int mf = o >> 2, nf = o & 3;
      f32x4 acc = {};
#pragma unroll
      for (int ks = 0; ks < 7; ks++) {
        bf16x8 af = *(const bf16x8*)&sm[(mf * 7 + ks) * 512 + lane * 8];
        bf16x8 bg = *(const bf16x8*)&sm[14336 + (nf * 7 + ks) * 512 + lane * 8];
        acc = __builtin_amdgcn_mfma_f32_16x16x32_bf16(af, bg, acc, 0, 0, 0);
      }
#pragma unroll
      for (int rr = 0; rr < 4; rr++) {
        int mj = m0 + mf * 16 + q * 4 + rr;
        int nk = n0 + nf * 16 + r;
        if (mj < 208 && nk < KP)
          Gp24[((size_t)(mj >> 4) * 7 + (nk >> 5)) * 512 +
               ((mj & 15) + 16 * ((nk >> 3) & 3)) * 8 + (nk & 7)] =
              f2bf(acc[rr]);
      }
    }
  } else if (id < 1280) {
    // Gf p=1,3 direct gather-copy: 8 groups of 26 rows per (b,w)
    int local = id - 1024;
    int rt = local & 7, bw = local >> 3;
    int b = bw >> 1, w = bw & 1;
    const float* A = (w ? a1 : a0) + (size_t)b * NK * NK;
    u16* Gp13 = Gf + ((size_t)b * 5 + 1 + 2 * w) * 13 * 7 * 512;
    int m0 = rt * 26;
    for (int u = t; u < 26 * 28; u += 256) {
      int ml = u / 28, kc = u - ml * 28;
      int m = m0 + ml;                                 // < 208
      u16 v[8] __attribute__((aligned(16)));
#pragma unroll
      for (int j = 0; j < 8; j++) {
        int k = kc * 8 + j;
        v[j] = (m < NK && k < NK) ? f2bf(A[(size_t)m * NK + k]) : (u16)0;
      }
      *(int4*)(Gp13 + ((size_t)(m >> 4) * 7 + (kc >> 2)) * 512 +
               ((m & 15) + 16 * (kc & 3)) * 8) = *(int4*)v;
    }
  } else if (id < 1312) {
    int local = id - 1280, b = local >> 1, half = local & 1;
    u16* Gp0 = Gf + (size_t)b * 5 * 13 * 7 * 512;      // p = 0
    for (int ci = t; ci < 104 * 28; ci += 256) {
      int jr = ci / 28, kc = ci - jr * 28;
      int j = half * 104 + jr;
      u16 v[8] __attribute__((aligned(16)));
      for (int jj = 0; jj < 8; jj++)
        v[jj] = (j == kc * 8 + jj && j < NK) ? (u16)0x3F80 : (u16)0;
      *(int4*)(Gp0 + ((size_t)(j >> 4) * 7 + (kc >> 2)) * 512 +
               ((j & 15) + 16 * (kc & 3)) * 8) = *(int4*)v;
    }
  } else {
    for (int ci = t; ci < 2560; ci += 256) {
      int o = ci / 40, kc = ci - o * 40;
      u16 v[8] __attribute__((aligned(16)));
      for (int j = 0; j < 8; j++) v[j] = f2bf(W[o * CIN + kc * 8 + j]);
      *(int4*)(Wbf + ((size_t)(o >> 4) * 10 + (kc >> 2)) * 512 +
               ((o & 15) + 16 * (kc & 3)) * 8) = *(int4*)v;
    }
  }
}

// ---- fused diffuse+conv (unchanged: known-good) ----------------------------
#define AG 17920            // A-stage base (u16); G region is [0, 17920)
__global__ __launch_bounds__(512, 4) void k_fused(
    const u16* __restrict__ Gf, const u16* __restrict__ Xf,
    const u16* __restrict__ Wbf, const float* __restrict__ bias,
    float* __restrict__ y) {
  __shared__ __align__(16) u16 lds[AG + 2 * 8192];  // 68,608 B -> 2 blocks/CU
  // bijective XCD swizzle: 3328 blocks, 416/XCD = 2 batches worth
  int id = blockIdx.x;
  int wg = (id & 7) * 416 + (id >> 3);
  int b = wg / 208, rem = wg % 208;
  int jt = rem >> 4, lt = rem & 15;
  int tid = threadIdx.x, wave = tid >> 6, lane = tid & 63;
  int r = lane & 15, q = lane >> 4;
  const u16* Gb = Gf + (size_t)b * 5 * 13 * 7 * 512;
  const u16* Xw = Xf + ((size_t)b * 256 + lt * 16) * 7 * 512;  // 16 tiles

  // stage G: 35 fragment tiles (p*7+ks), each one contiguous 1 KB DMA
  for (int i2 = 0; i2 < 5; i2++) {
    int tile = i2 * 8 + wave;            // wave-uniform
    if (tile < 35) {
      int p = tile / 7, ks = tile - p * 7;
      g2l16(Gb + ((size_t)(p * 13 + jt) * 7 + ks) * 512 + lane * 8,
            &lds[tile * 512 + lane * 8]);
    }
  }
  // prologue: stage ks=0 into buf0 (wave-private tiles wave*2+{0,1})
  for (int i2 = 0; i2 < 2; i2++) {
    int tl = wave * 2 + i2;
    g2l16(Xw + (size_t)tl * 7 * 512 + lane * 8, &lds[AG + tl * 512 + lane * 8]);
  }
  asm volatile("s_waitcnt vmcnt(2)" ::: "memory");  // G landed; stage0 in flight
  __builtin_amdgcn_s_barrier();                     // G visible to all waves

  f32x4 acc1[5][2] = {};
#pragma unroll
  for (int ks = 0; ks < 7; ks++) {
    int cur = ks & 1;
    if (ks < 6) {                      // stage ks+1 into other buffer
      for (int i2 = 0; i2 < 2; i2++) {
        int tl = wave * 2 + i2;
        g2l16(Xw + ((size_t)tl * 7 + ks + 1) * 512 + lane * 8,
              &lds[AG + (cur ^ 1) * 8192 + tl * 512 + lane * 8]);
      }
      asm volatile("s_waitcnt vmcnt(2)" ::: "memory");  // buf[cur] ready (mine)
    } else {
      asm volatile("s_waitcnt vmcnt(0)" ::: "memory");
    }
    bf16x8 af0 = *(const bf16x8*)&lds[AG + cur * 8192 + (wave * 2 + 0) * 512 + lane * 8];
    bf16x8 af1 = *(const bf16x8*)&lds[AG + cur * 8192 + (wave * 2 + 1) * 512 + lane * 8];
    __builtin_amdgcn_s_setprio(1);
#pragma unroll
    for (int p = 0; p < 5; p++) {
      bf16x8 bg = *(const bf16x8*)&lds[(p * 7 + ks) * 512 + lane * 8];
      acc1[p][0] = __builtin_amdgcn_mfma_f32_16x16x32_bf16(af0, bg, acc1[p][0], 0, 0, 0);
      acc1[p][1] = __builtin_amdgcn_mfma_f32_16x16x32_bf16(af1, bg, acc1[p][1], 0, 0, 0);
    }
    __builtin_amdgcn_s_setprio(0);
  }
  __syncthreads();   // all waves done with G + A-stage; reuse LDS for T

  // write T[p][j][t][c] (stride 72 u16, 16B-aligned rows; c XOR-swizzle by j)
#pragma unroll
  for (int p = 0; p < 5; p++)
#pragma unroll
    for (int mf = 0; mf < 2; mf++) {
      int m = (wave * 2 + mf) * 16 + q * 4;
      int tt = m >> 6, c = m & 63;
      int cs = c ^ ((r & 7) << 3);
      int idxT = ((p * 16 + r) * 4 + tt) * 72 + cs;
      u16 v0 = f2bf(acc1[p][mf][0]), v1 = f2bf(acc1[p][mf][1]);
      u16 v2 = f2bf(acc1[p][mf][2]), v3 = f2bf(acc1[p][mf][3]);
      *(uint2*)&lds[idxT] = make_uint2((unsigned)v0 | ((unsigned)v1 << 16),
                                       (unsigned)v2 | ((unsigned)v3 << 16));
    }
  // prefetch all W fragments to VGPRs (contiguous from Wf); fly across barrier
  int mo = wave >> 1, nh = (wave & 1) * 2;
  const u16* Wt = Wbf + (size_t)mo * 10 * 512 + lane * 8;
  bf16x8 aw[10];
#pragma unroll
  for (int ks = 0; ks < 10; ks++) aw[ks] = *(const bf16x8*)(Wt + ks * 512);
  __syncthreads();

  // GEMM-2: y tile 64(o) x 64(j,t), K=320=(p,c). No barriers.
  f32x4 acc2[2] = {};
#pragma unroll
  for (int ks = 0; ks < 10; ks++) {
    int p = ks >> 1, c0 = (ks & 1) * 32;
#pragma unroll
    for (int nf = 0; nf < 2; nf++) {
      int n = (nh + nf) * 16 + r;
      int j = n >> 2, tt = n & 3;
      int cs = (c0 + q * 8) ^ ((j & 7) << 3);
      bf16x8 bt = *(const bf16x8*)&lds[((p * 16 + j) * 4 + tt) * 72 + cs];
      acc2[nf] = __builtin_amdgcn_mfma_f32_16x16x32_bf16(aw[ks], bt, acc2[nf], 0, 0, 0);
    }
  }

  // epilogue: per (o, j) the 4 t-values are 16B-contiguous in y
  int o0 = mo * 16 + q * 4;
  float4 bv = *(const float4*)&bias[o0];
  float* yb = y + (size_t)b * 64 * NKL;
#pragma unroll
  for (int nf = 0; nf < 2; nf++) {
    int n = (nh + nf) * 16 + r;
    int j = n >> 2, tt = n & 3;
    int jnode = jt * 16 + j;
    if (jnode < NK) {
      int col = jnode * 64 + lt * 4 + tt;
      yb[(size_t)(o0 + 0) * NKL + col] = acc2[nf][0] + bv.x;
      yb[(size_t)(o0 + 1) * NKL + col] = acc2[nf][1] + bv.y;
      yb[(size_t)(o0 + 2) * NKL + col] = acc2[nf][2] + bv.z;
      yb[(size_t)(o0 + 3) * NKL + col] = acc2[nf][3] + bv.w;
    }
  }
}

extern "C" void kernel_launch(void* const* d_in, const int* in_sizes, int n_in,
                              void* d_out, int out_size, void* d_ws, size_t ws_size,
                              hipStream_t stream) {
  const float* x = (const float*)d_in[0];
  const float* a0 = (const float*)d_in[1];
  const float* a1 = (const float*)d_in[2];
  const float* W = (const float*)d_in[3];
  const float* bias = (const float*)d_in[4];
  float* y = (float*)d_out;
  char* ws = (char*)d_ws;

  size_t off = 0;
  auto alloc = [&](size_t bytes) {
    size_t o = off;
    off = (off + bytes + 511) & ~(size_t)511;
    return o;
  };
  size_t o_Xf = alloc((size_t)NB * 256 * 7 * 512 * 2);       // 29.4 MB
  size_t o_Gf = alloc((size_t)NB * 5 * 13 * 7 * 512 * 2);    // 7.5 MB
  size_t o_Wf = alloc((size_t)4 * 10 * 512 * 2);             // 40 KB
  (void)ws_size;

  u16* Xf = (u16*)(ws + o_Xf);
  u16* Gf = (u16*)(ws + o_Gf);
  u16* Wf = (u16*)(ws + o_Wf);

  k_prep<<<dim3(1313), 256, 0, stream>>>(x, a0, a1, W, Xf, Gf, Wf);
  k_fused<<<dim3(16 * 13 * 16), 512, 0, stream>>>(Gf, Xf, Wf, bias, y);
}